// Round 1
// baseline (466.695 us; speedup 1.0000x reference)
//
#include <hip/hip_runtime.h>
#include <hip/hip_bf16.h>

// Problem constants
#define B_ 1024
#define S_ 100
#define IN_ 100
#define H_ 128
#define MID_ 32
#define OUT_ 2
#define P_ (B_ * S_)           // 102400 positions
#define RSQRT_H 0.08838834764831845f  // 1/sqrt(128)

// ---------------------------------------------------------------------------
// Kernel 0: Wqk = Wq @ Wk^T   (128x128 @ 128x128^T) — tiny
// ---------------------------------------------------------------------------
__global__ __launch_bounds__(256) void wqk_kernel(const float* __restrict__ Wq,
                                                  const float* __restrict__ Wk,
                                                  float* __restrict__ Wqk) {
    int idx = blockIdx.x * 256 + threadIdx.x;  // 0..16383
    int h1 = idx >> 7, h2 = idx & 127;
    float acc = 0.f;
    for (int k = 0; k < H_; ++k)
        acc += Wq[h1 * H_ + k] * Wk[h2 * H_ + k];
    Wqk[idx] = acc;
}

// ---------------------------------------------------------------------------
// Generic tiled fp32 GEMM with fused epilogues.
// C[M,N] = A[M,K] @ Bm[K,N]  (+ epilogue)
// EPI 0: none
// EPI 1: relu(acc + bias[n]) + pe[(row % S_) * N + n]
// EPI 2: acc + bias[n]
// EPI 3: relu(acc + bias[n])
// Tile: BM=64, BN=64, BK=16; 256 threads, 4x4 microtile per thread.
// ---------------------------------------------------------------------------
template <int EPI>
__global__ __launch_bounds__(256) void gemm_epi(const float* __restrict__ A,
                                                const float* __restrict__ Bm,
                                                float* __restrict__ C,
                                                int M, int N, int K,
                                                const float* __restrict__ bias,
                                                const float* __restrict__ pe) {
    constexpr int BM = 64, BN = 64, BK = 16, TM = 4, TN = 4;
    __shared__ float As[BK][BM + 4];  // +4 keeps 16B alignment, breaks conflicts
    __shared__ float Bs[BK][BN + 4];

    int tid = threadIdx.x;
    int tr = tid / (BN / TN);  // 0..15
    int tc = tid % (BN / TN);  // 0..15
    int block_row = blockIdx.y * BM;
    int block_col = blockIdx.x * BN;

    float acc[TM][TN];
#pragma unroll
    for (int i = 0; i < TM; ++i)
#pragma unroll
        for (int j = 0; j < TN; ++j) acc[i][j] = 0.f;

    for (int k0 = 0; k0 < K; k0 += BK) {
        // Load A tile (BM x BK), stored transposed into As[k][m]
#pragma unroll
        for (int i = tid; i < BM * BK; i += 256) {
            int r = i / BK, c = i % BK;
            int gr = block_row + r, gc = k0 + c;
            As[c][r] = (gr < M && gc < K) ? A[(size_t)gr * K + gc] : 0.f;
        }
        // Load B tile (BK x BN)
#pragma unroll
        for (int i = tid; i < BK * BN; i += 256) {
            int r = i / BN, c = i % BN;
            int gr = k0 + r, gc = block_col + c;
            Bs[r][c] = (gr < K && gc < N) ? Bm[(size_t)gr * N + gc] : 0.f;
        }
        __syncthreads();
#pragma unroll
        for (int kk = 0; kk < BK; ++kk) {
            float a[TM], b[TN];
#pragma unroll
            for (int i = 0; i < TM; ++i) a[i] = As[kk][tr * TM + i];
#pragma unroll
            for (int j = 0; j < TN; ++j) b[j] = Bs[kk][tc * TN + j];
#pragma unroll
            for (int i = 0; i < TM; ++i)
#pragma unroll
                for (int j = 0; j < TN; ++j) acc[i][j] += a[i] * b[j];
        }
        __syncthreads();
    }

#pragma unroll
    for (int i = 0; i < TM; ++i) {
        int gr = block_row + tr * TM + i;
        if (gr >= M) continue;
#pragma unroll
        for (int j = 0; j < TN; ++j) {
            int gc = block_col + tc * TN + j;
            if (gc >= N) continue;
            float v = acc[i][j];
            if (EPI == 1) v = fmaxf(v + bias[gc], 0.f) + pe[(gr % S_) * N + gc];
            else if (EPI == 2) v = v + bias[gc];
            else if (EPI == 3) v = fmaxf(v + bias[gc], 0.f);
            C[(size_t)gr * N + gc] = v;
        }
    }
}

// ---------------------------------------------------------------------------
// Attention kernel: per position p -> scores (5), softmax -> w (to d_out),
// nsum = sum_m w[m]*h[neighbor]  (written over kq buffer in place).
// 4 lanes per position, each handling 32 of 128 dims.
// ---------------------------------------------------------------------------
__global__ __launch_bounds__(256) void attn_kernel(const float* __restrict__ h,
                                                   float* __restrict__ kq_nsum,
                                                   float* __restrict__ wout) {
    int tid = threadIdx.x;
    int sub = tid & 3;                      // 0..3 -> dim chunk
    int pos = blockIdx.x * 64 + (tid >> 2); // grid sized exactly
    int s = pos % S_;

    const float4* kqp = (const float4*)(kq_nsum + (size_t)pos * H_ + sub * 32);
    float4 kqv[8];
#pragma unroll
    for (int i = 0; i < 8; ++i) kqv[i] = kqp[i];

    float sc[5];
#pragma unroll
    for (int m = 0; m < 5; ++m) {
        int ns = s + 2 - m;
        float p = 0.f;
        if (ns >= 0 && ns < S_) {
            const float4* hp = (const float4*)(h + (size_t)(pos + 2 - m) * H_ + sub * 32);
#pragma unroll
            for (int i = 0; i < 8; ++i) {
                float4 hv = hp[i];
                p += hv.x * kqv[i].x + hv.y * kqv[i].y + hv.z * kqv[i].z + hv.w * kqv[i].w;
            }
        }
        sc[m] = p;
    }
    // reduce partial dots across the 4 lanes of this position
#pragma unroll
    for (int m = 0; m < 5; ++m) {
        sc[m] += __shfl_xor(sc[m], 1, 4);
        sc[m] += __shfl_xor(sc[m], 2, 4);
        sc[m] *= RSQRT_H;
    }
    float mx = sc[0];
#pragma unroll
    for (int m = 1; m < 5; ++m) mx = fmaxf(mx, sc[m]);
    float e[5], ssum = 0.f;
#pragma unroll
    for (int m = 0; m < 5; ++m) { e[m] = expf(sc[m] - mx); ssum += e[m]; }
    float inv = 1.f / ssum;
    float w[5];
#pragma unroll
    for (int m = 0; m < 5; ++m) w[m] = e[m] * inv;

    if (sub == 0) {
#pragma unroll
        for (int m = 0; m < 5; ++m) wout[(size_t)pos * 5 + m] = w[m];
    }

    // nsum (overwrites kq in place — safe: read-before-write same indices)
    float4 acc[8];
#pragma unroll
    for (int i = 0; i < 8; ++i) acc[i] = make_float4(0.f, 0.f, 0.f, 0.f);
#pragma unroll
    for (int m = 0; m < 5; ++m) {
        int ns = s + 2 - m;
        if (ns < 0 || ns >= S_) continue;
        const float4* hp = (const float4*)(h + (size_t)(pos + 2 - m) * H_ + sub * 32);
#pragma unroll
        for (int i = 0; i < 8; ++i) {
            float4 hv = hp[i];
            acc[i].x += w[m] * hv.x;
            acc[i].y += w[m] * hv.y;
            acc[i].z += w[m] * hv.z;
            acc[i].w += w[m] * hv.w;
        }
    }
    float4* np = (float4*)(kq_nsum + (size_t)pos * H_ + sub * 32);
#pragma unroll
    for (int i = 0; i < 8; ++i) np[i] = acc[i];
}

// ---------------------------------------------------------------------------
// Output kernel: out = mid @ W3 + b3  (P x 32 @ 32 x 2)
// 256 positions per block; mid tile staged through LDS for coalescing.
// ---------------------------------------------------------------------------
__global__ __launch_bounds__(256) void out_kernel(const float* __restrict__ mid,
                                                  const float* __restrict__ W3,
                                                  const float* __restrict__ b3,
                                                  float* __restrict__ out) {
    __shared__ float smid[256 * 33];
    int tid = threadIdx.x;
    size_t base = (size_t)blockIdx.x * 256 * MID_;
#pragma unroll
    for (int j = 0; j < 32; ++j) {
        int idx = tid + j * 256;
        int r = idx >> 5, c = idx & 31;
        smid[r * 33 + c] = mid[base + idx];
    }
    __syncthreads();
    float o0 = b3[0], o1 = b3[1];
#pragma unroll
    for (int k = 0; k < MID_; ++k) {
        float mv = smid[tid * 33 + k];
        o0 += mv * W3[k * 2 + 0];
        o1 += mv * W3[k * 2 + 1];
    }
    size_t p = (size_t)blockIdx.x * 256 + tid;
    out[p * 2 + 0] = o0;
    out[p * 2 + 1] = o1;
}

// ---------------------------------------------------------------------------
extern "C" void kernel_launch(void* const* d_in, const int* in_sizes, int n_in,
                              void* d_out, int out_size, void* d_ws, size_t ws_size,
                              hipStream_t stream) {
    const float* x  = (const float*)d_in[0];
    const float* W1 = (const float*)d_in[1];
    const float* b1 = (const float*)d_in[2];
    const float* Wq = (const float*)d_in[3];
    const float* Wk = (const float*)d_in[4];
    const float* Wv = (const float*)d_in[5];
    const float* bv = (const float*)d_in[6];
    const float* W2 = (const float*)d_in[7];
    const float* b2 = (const float*)d_in[8];
    const float* W3 = (const float*)d_in[9];
    const float* b3 = (const float*)d_in[10];
    const float* pe = (const float*)d_in[11];

    float* out  = (float*)d_out;             // (B,S,2)  = 204800 floats
    float* wout = out + (size_t)P_ * OUT_;   // (B,S,1,5) = 512000 floats

    // Workspace layout: h | kq(->nsum->mid) | Wqk   (~105 MB)
    float* h   = (float*)d_ws;
    float* kq  = h + (size_t)P_ * H_;
    float* wqk = kq + (size_t)P_ * H_;

    // 0) Wqk = Wq @ Wk^T
    wqk_kernel<<<64, 256, 0, stream>>>(Wq, Wk, wqk);

    // 1) h = relu(x @ W1 + b1) + pe    (M=P, K=100, N=128)
    dim3 gH(2, P_ / 64);
    gemm_epi<1><<<gH, 256, 0, stream>>>(x, W1, h, P_, H_, IN_, b1, pe);

    // 2) kq = h @ Wqk                  (M=P, K=128, N=128)
    gemm_epi<0><<<gH, 256, 0, stream>>>(h, wqk, kq, P_, H_, H_, nullptr, nullptr);

    // 3) scores/softmax -> w (d_out), nsum (over kq buffer)
    attn_kernel<<<P_ / 64, 256, 0, stream>>>(h, kq, wout);

    // 4) context = nsum @ Wv + bv      (-> h buffer, no longer needed)
    gemm_epi<2><<<gH, 256, 0, stream>>>(kq, Wv, h, P_, H_, H_, bv, nullptr);

    // 5) mid = relu(context @ W2 + b2) (M=P, K=128, N=32 -> kq buffer)
    dim3 gM(1, P_ / 64);
    gemm_epi<3><<<gM, 256, 0, stream>>>(h, W2, kq, P_, MID_, H_, b2, nullptr);

    // 6) out = mid @ W3 + b3
    out_kernel<<<P_ / 256, 256, 0, stream>>>(kq, W3, b3, out);
}

// Round 2
// 150.584 us; speedup vs baseline: 3.0992x; 3.0992x over previous
//
#include <hip/hip_runtime.h>
#include <hip/hip_bf16.h>

#define B_ 1024
#define S_ 100
#define IN_ 100
#define H_ 128
#define MID_ 32
#define OUT_ 2
#define P_ (B_ * S_)
#define RSQRT_H 0.08838834764831845f
#define LSTR 136   // LDS row stride in bf16 elems: 272 B -> max 2-way bank conflict (free)
#define MROWS 112  // 7 M-tiles of 16 rows (>= 100)

typedef __attribute__((ext_vector_type(8))) short short8;
typedef __attribute__((ext_vector_type(4))) float float4v;

__device__ __forceinline__ float bf2f(ushort u) {
    union { unsigned u; float f; } c; c.u = ((unsigned)u) << 16; return c.f;
}
__device__ __forceinline__ ushort f2bf(float x) {
    union { float f; unsigned u; } c; c.f = x;
    unsigned r = c.u + 0x7FFFu + ((c.u >> 16) & 1u);  // RNE
    return (ushort)(r >> 16);
}

// ---------------------------------------------------------------------------
// Prep A: W1T[n][k]=W1[k][n] (k<100 else 0), WvT[n][k]=Wv[k][n], W2T[n][k]=W2[k][n]
// All bf16, row stride 128 (k padded to 128). 144 blocks x 256 = 36864 elems.
// ---------------------------------------------------------------------------
__global__ __launch_bounds__(256) void prep_transpose(const float* __restrict__ W1,
                                                      const float* __restrict__ Wv,
                                                      const float* __restrict__ W2,
                                                      ushort* __restrict__ W1T,
                                                      ushort* __restrict__ WvT,
                                                      ushort* __restrict__ W2T) {
    int g = blockIdx.x * 256 + threadIdx.x;
    if (g < 16384) {
        int n = g >> 7, k = g & 127;
        W1T[g] = (k < IN_) ? f2bf(W1[k * H_ + n]) : (ushort)0;
    } else if (g < 32768) {
        int e = g - 16384; int n = e >> 7, k = e & 127;
        WvT[e] = f2bf(Wv[k * H_ + n]);
    } else {
        int e = g - 32768; int n = e >> 7, k = e & 127;
        W2T[e] = f2bf(W2[k * MID_ + n]);
    }
}

// ---------------------------------------------------------------------------
// Prep B: WqkT[n][k] = sum_j Wq[k][j] * Wk[n][j]  (bf16 out, [n][k] layout)
// 16 blocks, each a 32(n) x 32(k) tile, K=128 staged in LDS.
// ---------------------------------------------------------------------------
__global__ __launch_bounds__(256) void prep_wqk(const float* __restrict__ Wq,
                                                const float* __restrict__ Wk,
                                                ushort* __restrict__ WqkT) {
    __shared__ float sq[32][132];  // Wq rows k0..k0+31 (pad 132 breaks conflicts)
    __shared__ float sk[32][132];  // Wk rows n0..n0+31
    int n0 = (blockIdx.x >> 2) * 32, k0 = (blockIdx.x & 3) * 32;
    int tid = threadIdx.x;
    for (int i = tid; i < 32 * 128; i += 256) {
        int r = i >> 7, c = i & 127;
        sq[r][c] = Wq[(k0 + r) * H_ + c];
        sk[r][c] = Wk[(n0 + r) * H_ + c];
    }
    __syncthreads();
    for (int i = tid; i < 1024; i += 256) {
        int kk = i & 31, nn = i >> 5;
        float a = 0.f;
        for (int j = 0; j < 128; ++j) a += sq[kk][j] * sk[nn][j];
        WqkT[(n0 + nn) * 128 + (k0 + kk)] = f2bf(a);
    }
}

// ---------------------------------------------------------------------------
// Fused per-sequence GEMM stage: C_lds[m][n] = epi(A_lds[m][128] @ WT^T)
// A_lds: bf16 [MROWS][LSTR]; WT: global bf16 [N][128] (B-transposed);
// wave w owns N-tiles {2w, 2w+1}; loops all 7 M-tiles; 16x16x32 bf16 MFMA.
// EPI 0: none | 1: relu(+bias)+pe, rows>=100 -> 0 | 2: +bias
// ---------------------------------------------------------------------------
template <int EPI>
__device__ __forceinline__ void mm_stage(const ushort* __restrict__ A_lds,
                                         const ushort* __restrict__ WT,
                                         ushort* __restrict__ C_lds,
                                         int wave, int lane,
                                         const float* __restrict__ bias,
                                         const float* __restrict__ pe) {
    int l15 = lane & 15, quad = lane >> 4;
    short8 bfrag[2][4];
#pragma unroll
    for (int nt = 0; nt < 2; ++nt) {
        int n = (wave * 2 + nt) * 16 + l15;
#pragma unroll
        for (int ks = 0; ks < 4; ++ks)
            bfrag[nt][ks] = *(const short8*)(WT + n * 128 + ks * 32 + quad * 8);
    }
    float biasv[2] = {0.f, 0.f};
    if (EPI != 0) {
#pragma unroll
        for (int nt = 0; nt < 2; ++nt) biasv[nt] = bias[(wave * 2 + nt) * 16 + l15];
    }
#pragma unroll
    for (int mt = 0; mt < 7; ++mt) {
        short8 afrag[4];
#pragma unroll
        for (int ks = 0; ks < 4; ++ks)
            afrag[ks] = *(const short8*)(A_lds + (mt * 16 + l15) * LSTR + ks * 32 + quad * 8);
#pragma unroll
        for (int nt = 0; nt < 2; ++nt) {
            float4v acc = {0.f, 0.f, 0.f, 0.f};
#pragma unroll
            for (int ks = 0; ks < 4; ++ks)
                acc = __builtin_amdgcn_mfma_f32_16x16x32_bf16(afrag[ks], bfrag[nt][ks], acc, 0, 0, 0);
            int n = (wave * 2 + nt) * 16 + l15;
#pragma unroll
            for (int i = 0; i < 4; ++i) {
                int row = mt * 16 + quad * 4 + i;
                float v = acc[i];
                if (EPI == 1) v = (row < S_) ? (fmaxf(v + biasv[nt], 0.f) + pe[row * H_ + n]) : 0.f;
                else if (EPI == 2) v = v + biasv[nt];
                C_lds[row * LSTR + n] = f2bf(v);
            }
        }
    }
}

// ---------------------------------------------------------------------------
// Megakernel: one block per batch row b. Everything after x stays in LDS.
// ---------------------------------------------------------------------------
__global__ __launch_bounds__(256) void fused_kernel(
    const float* __restrict__ x, const ushort* __restrict__ W1T,
    const ushort* __restrict__ WqkT, const ushort* __restrict__ WvT,
    const ushort* __restrict__ W2T,
    const float* __restrict__ b1, const float* __restrict__ bv,
    const float* __restrict__ b2, const float* __restrict__ W3,
    const float* __restrict__ b3, const float* __restrict__ pe,
    float* __restrict__ out, float* __restrict__ wout) {
    __shared__ ushort klds[MROWS * LSTR];  // x -> kq -> nsum -> mid
    __shared__ ushort xh[MROWS * LSTR];    // h -> ctx
    int tid = threadIdx.x, wave = tid >> 6, lane = tid & 63;
    int b = blockIdx.x;
    const float* xb = x + (size_t)b * (S_ * IN_);

    // zero klds (pad rows/cols must be 0 for the K-padded and M-padded MFMAs)
    for (int i = tid; i < MROWS * LSTR; i += 256) klds[i] = 0;
    __syncthreads();
    // load x -> klds as bf16 [m][k]
    for (int i = tid; i < S_ * IN_; i += 256) {
        int m = i / IN_, k = i - m * IN_;
        klds[m * LSTR + k] = f2bf(xb[i]);
    }
    __syncthreads();
    // S1: h = relu(x@W1 + b1) + pe  -> xh
    mm_stage<1>(klds, W1T, xh, wave, lane, b1, pe);
    __syncthreads();
    // S2: kq = h @ (Wq Wk^T)        -> klds
    mm_stage<0>(xh, WqkT, klds, wave, lane, nullptr, nullptr);
    __syncthreads();
    // S3: scores -> softmax -> w (global) + nsum (in-place over klds rows)
    if (tid < 2 * S_) {
        int r = tid >> 1, half = tid & 1;  // 2 threads per row, 64 dims each
        const ushort* kqr = klds + r * LSTR + half * 64;
        float kqf[64];
#pragma unroll
        for (int c = 0; c < 8; ++c) {
            short8 v = *(const short8*)(kqr + c * 8);
#pragma unroll
            for (int j = 0; j < 8; ++j) kqf[c * 8 + j] = bf2f((ushort)v[j]);
        }
        float sc[5];
#pragma unroll
        for (int m = 0; m < 5; ++m) {
            int nr = r + 2 - m;  // neighbor index m == x[i + ATTEN - m]
            float p = 0.f;
            if (nr >= 0 && nr < S_) {
                const ushort* hr = xh + nr * LSTR + half * 64;
#pragma unroll
                for (int c = 0; c < 8; ++c) {
                    short8 v = *(const short8*)(hr + c * 8);
#pragma unroll
                    for (int j = 0; j < 8; ++j) p += bf2f((ushort)v[j]) * kqf[c * 8 + j];
                }
            }
            sc[m] = p;
        }
#pragma unroll
        for (int m = 0; m < 5; ++m)
            sc[m] = (sc[m] + __shfl_xor(sc[m], 1)) * RSQRT_H;  // pair-reduce halves
        float mx = sc[0];
#pragma unroll
        for (int m = 1; m < 5; ++m) mx = fmaxf(mx, sc[m]);
        float e[5], ss = 0.f;
#pragma unroll
        for (int m = 0; m < 5; ++m) { e[m] = expf(sc[m] - mx); ss += e[m]; }
        float inv = 1.f / ss;
        float w5[5];
#pragma unroll
        for (int m = 0; m < 5; ++m) w5[m] = e[m] * inv;
        if (half == 0) {
            float* wp = wout + (size_t)b * (S_ * 5) + r * 5;
#pragma unroll
            for (int m = 0; m < 5; ++m) wp[m] = w5[m];
        }
        // nsum[r] = sum_m w[m] * h[r+2-m]  (bias bv absorbed post-GEMM; sum w = 1)
        float acc[64];
#pragma unroll
        for (int c = 0; c < 64; ++c) acc[c] = 0.f;
#pragma unroll
        for (int m = 0; m < 5; ++m) {
            int nr = r + 2 - m;
            if (nr < 0 || nr >= S_) continue;
            float wm = w5[m];
            const ushort* hr = xh + nr * LSTR + half * 64;
#pragma unroll
            for (int c = 0; c < 8; ++c) {
                short8 v = *(const short8*)(hr + c * 8);
#pragma unroll
                for (int j = 0; j < 8; ++j) acc[c * 8 + j] += wm * bf2f((ushort)v[j]);
            }
        }
        ushort* op = klds + r * LSTR + half * 64;  // own half-row only: race-free
#pragma unroll
        for (int c = 0; c < 8; ++c) {
            short8 v;
#pragma unroll
            for (int j = 0; j < 8; ++j) v[j] = (short)f2bf(acc[c * 8 + j]);
            *(short8*)(op + c * 8) = v;
        }
    }
    __syncthreads();
    // S4: ctx = nsum @ Wv + bv  -> xh
    mm_stage<2>(klds, WvT, xh, wave, lane, bv, nullptr);
    __syncthreads();
    // S5: mid = relu(ctx @ W2 + b2) -> klds cols 0..31 (only 2 N-tiles; split M over waves)
    {
        int l15 = lane & 15, quad = lane >> 4;
        short8 bfrag[2][4];
#pragma unroll
        for (int nt = 0; nt < 2; ++nt)
#pragma unroll
            for (int ks = 0; ks < 4; ++ks)
                bfrag[nt][ks] = *(const short8*)(W2T + (nt * 16 + l15) * 128 + ks * 32 + quad * 8);
        float biasv[2] = {b2[l15], b2[16 + l15]};
        for (int mt = wave; mt < 7; mt += 4) {
            short8 afrag[4];
#pragma unroll
            for (int ks = 0; ks < 4; ++ks)
                afrag[ks] = *(const short8*)(xh + (mt * 16 + l15) * LSTR + ks * 32 + quad * 8);
#pragma unroll
            for (int nt = 0; nt < 2; ++nt) {
                float4v acc = {0.f, 0.f, 0.f, 0.f};
#pragma unroll
                for (int ks = 0; ks < 4; ++ks)
                    acc = __builtin_amdgcn_mfma_f32_16x16x32_bf16(afrag[ks], bfrag[nt][ks], acc, 0, 0, 0);
#pragma unroll
                for (int i = 0; i < 4; ++i) {
                    int row = mt * 16 + quad * 4 + i;
                    klds[row * LSTR + nt * 16 + l15] = f2bf(fmaxf(acc[i] + biasv[nt], 0.f));
                }
            }
        }
    }
    __syncthreads();
    // S6: out = mid @ W3 + b3  (K=32, N=2) -- vector math
    if (tid < S_) {
        int r = tid;
        float o0 = b3[0], o1 = b3[1];
#pragma unroll
        for (int k = 0; k < MID_; ++k) {
            float mv = bf2f(klds[r * LSTR + k]);
            o0 += mv * W3[k * 2];
            o1 += mv * W3[k * 2 + 1];
        }
        float* op = out + (size_t)b * (S_ * OUT_) + r * OUT_;
        op[0] = o0; op[1] = o1;
    }
}

// ---------------------------------------------------------------------------
extern "C" void kernel_launch(void* const* d_in, const int* in_sizes, int n_in,
                              void* d_out, int out_size, void* d_ws, size_t ws_size,
                              hipStream_t stream) {
    const float* x  = (const float*)d_in[0];
    const float* W1 = (const float*)d_in[1];
    const float* b1 = (const float*)d_in[2];
    const float* Wq = (const float*)d_in[3];
    const float* Wk = (const float*)d_in[4];
    const float* Wv = (const float*)d_in[5];
    const float* bv = (const float*)d_in[6];
    const float* W2 = (const float*)d_in[7];
    const float* b2 = (const float*)d_in[8];
    const float* W3 = (const float*)d_in[9];
    const float* b3 = (const float*)d_in[10];
    const float* pe = (const float*)d_in[11];

    float* out  = (float*)d_out;             // (B,S,2)
    float* wout = out + (size_t)P_ * OUT_;   // (B,S,1,5)

    ushort* W1T  = (ushort*)d_ws;            // [128][128] bf16
    ushort* WqkT = W1T + 16384;              // [128][128] bf16
    ushort* WvT  = WqkT + 16384;             // [128][128] bf16
    ushort* W2T  = WvT + 16384;              // [32][128]  bf16

    prep_transpose<<<144, 256, 0, stream>>>(W1, Wv, W2, W1T, WvT, W2T);
    prep_wqk<<<16, 256, 0, stream>>>(Wq, Wk, WqkT);
    fused_kernel<<<B_, 256, 0, stream>>>(x, W1T, WqkT, WvT, W2T,
                                         b1, bv, b2, W3, b3, pe, out, wout);
}